// Round 6
// baseline (201.767 us; speedup 1.0000x reference)
//
#include <hip/hip_runtime.h>
#include <hip/hip_bf16.h>
#include <math.h>

// B,T,D,H = 64,2048,256,5
constexpr int BB   = 64;
constexpr int TT   = 2048;
constexpr int DD   = 256;
constexpr int HH   = 5;
constexpr int SEG  = 32;             // segments per batch row
constexpr int TSEG = TT / SEG;       // 64 timesteps per block
constexpr int PSTR = 272;            // partial row stride: [0]=l, [16+d]=acc (64B-aligned)

typedef float fvec4 __attribute__((ext_vector_type(4)));  // nontemporal-load-able

// fast tanh: 1 - 2/(e^{2x}+1). |err| ~1e-6, threshold is 1.7e-3.
__device__ __forceinline__ float ftanh(float x) {
    float e = __expf(2.0f * x);
    return 1.0f - 2.0f * __builtin_amdgcn_rcpf(e + 1.0f);
}

// DPP add on the VALU pipe (vs __shfl_xor -> ds_swizzle on the LDS pipe).
template <int CTRL>
__device__ __forceinline__ float dpp_add(float x) {
    int s = __builtin_amdgcn_update_dpp(0, __float_as_int(x), CTRL, 0xf, 0xf, true);
    return x + __int_as_float(s);
}
// 32-lane-half sum via row_shr 1/2/4/8 + row_bcast15. Valid in lanes 31 and 63.
__device__ __forceinline__ float half_sum_dpp(float v) {
    v = dpp_add<0x111>(v);   // row_shr:1
    v = dpp_add<0x112>(v);   // row_shr:2
    v = dpp_add<0x114>(v);   // row_shr:4
    v = dpp_add<0x118>(v);   // row_shr:8
    v = dpp_add<0x142>(v);   // row_bcast15 -> lane31 = sum(0..31), lane63 = sum(32..63)
    return v;
}

// One block = (b, 64-timestep segment). x register-resident end-to-end.
// |intermed| <= sum|uwr| ~ 0.5 -> softmax WITHOUT max-shift; partials are
// pure sums. Cross-segment merge in a second kernel.
//
// R5: contiguous NT lane mapping (lane owns d0..d0+3 and 128+d0..+3; each
// load instruction covers gap-free 512B) — validated, -6.7us.
// R6: occupancy 3->4 blocks/CU. Two-pass dot (reuse one 20-reg W fragment,
// accumulate upper-half into phl via LDS += by the owning lanes) drops peak
// VGPR ~135 -> ~110 so launch_bounds(256,4) fits without spill. PSTR 272:
// part acc block 64B-aligned.
__global__ __launch_bounds__(256, 4)
void seg_kernel(const float* __restrict__ x_temp,
                const float* __restrict__ x_fea,
                const int* __restrict__ mask,            // bool -> int32 per harness
                const float* __restrict__ W_temp,        // (D,H) row-major
                const float* __restrict__ b_temp,
                const float* __restrict__ W_fea,         // (1,H)
                const float* __restrict__ b_fea,
                const float* __restrict__ uw,            // (H,H)
                float* __restrict__ part)                // (B*SEG, PSTR)
{
    __shared__ alignas(16) float im[2 * TSEG];     // interleaved {e_r, maskf_r}
    __shared__ alignas(16) float phl[TSEG][6];     // reduced dots ph[r][h] (+pad)
    __shared__ float lsh0, lsh1;                   // half lsums (rows 0..31 / 32..63)
    __shared__ alignas(16) float ldsw[8 * 264];    // per-(wave,half) acc partials

    const int tid  = threadIdx.x;
    const int l    = tid & 63;
    const int wave = tid >> 6;
    const int half = l >> 5;
    const int l32  = l & 31;
    const int blk  = blockIdx.x;
    const int b    = blk >> 5;          // blk / SEG
    const int seg  = blk & (SEG - 1);
    const int t0   = seg * TSEG;
    const size_t rowbase = (size_t)b * TT;
    const float* xbase = x_temp + (rowbase + t0) * (size_t)DD;

    if (tid < TSEG) im[2 * tid + 1] = mask[rowbase + t0 + tid] ? 1.0f : 0.0f;

    // ---- stage: 8 rows per (wave,half); lane owns d0..d0+3 and 128+d0..+3 ----
    const int d0 = l32 * 4;
    fvec4 xq[8][2];
#pragma unroll
    for (int it = 0; it < 8; ++it) {
        const float* p = xbase + (it * 8 + wave * 2 + half) * DD;
        xq[it][0] = __builtin_nontemporal_load((const fvec4*)(p + d0));
        xq[it][1] = __builtin_nontemporal_load((const fvec4*)(p + 128 + d0));
    }

    // ---- two-pass dot + DPP 32-half reduce; lanes 31/63 own row r in phl ----
    // Pass A: W rows d0..d0+3 (20 floats). One 20-reg fragment, reused in B.
    float wv[20];
    {
        const fvec4* wp = (const fvec4*)(W_temp + d0 * HH);
#pragma unroll
        for (int q = 0; q < 5; ++q) ((fvec4*)wv)[q] = wp[q];
    }
#pragma unroll
    for (int it = 0; it < 8; ++it) {
        const int r = it * 8 + wave * 2 + half;
        const fvec4 a0 = xq[it][0];
#pragma unroll
        for (int h = 0; h < HH; ++h) {
            float ph = a0[0] * wv[0 * HH + h] + a0[1] * wv[1 * HH + h]
                     + a0[2] * wv[2 * HH + h] + a0[3] * wv[3 * HH + h];
            ph = half_sum_dpp(ph);                // valid in lanes 31 / 63
            if (l32 == 31) phl[r][h] = ph;        // owning lane writes
        }
    }
    // Pass B: W rows 128+d0.. ; same lanes accumulate into phl (same-wave LDS
    // ordering, no barrier needed).
    {
        const fvec4* wp = (const fvec4*)(W_temp + (128 + d0) * HH);
#pragma unroll
        for (int q = 0; q < 5; ++q) ((fvec4*)wv)[q] = wp[q];
    }
#pragma unroll
    for (int it = 0; it < 8; ++it) {
        const int r = it * 8 + wave * 2 + half;
        const fvec4 a1 = xq[it][1];
#pragma unroll
        for (int h = 0; h < HH; ++h) {
            float ph = a1[0] * wv[0 * HH + h] + a1[1] * wv[1 * HH + h]
                     + a1[2] * wv[2 * HH + h] + a1[3] * wv[3 * HH + h];
            ph = half_sum_dpp(ph);
            if (l32 == 31) phl[r][h] += ph;
        }
    }
    __syncthreads();

    // ---- finish phase: ONE full wave (lanes 0..63 = rows 0..63) ----
    if (tid < TSEG) {
        const int r = tid;
        float wfea[HH], bfea[HH], btmp[HH], uwr[HH];
#pragma unroll
        for (int h = 0; h < HH; ++h) {
            wfea[h] = W_fea[h]; bfea[h] = b_fea[h]; btmp[h] = b_temp[h];
            float s = 0.f;
#pragma unroll
            for (int h2 = 0; h2 < HH; ++h2) s += uw[h * HH + h2];
            uwr[h] = s;  // sum(hadamard@uw+b,-1) = hadamard.uwr + const (cancels)
        }
        const float xf = x_fea[rowbase + t0 + r];
        float inter = 0.f;
#pragma unroll
        for (int h = 0; h < HH; ++h)
            inter += ftanh(phl[r][h] + btmp[h]) * ftanh(xf * wfea[h] + bfea[h]) * uwr[h];
        const float e = im[2 * r + 1] * __expf(inter);  // masked exp, no max-shift
        im[2 * r] = e;
        const float ls = half_sum_dpp(e);   // lane31: rows 0..31, lane63: rows 32..63
        if (r == 31) lsh0 = ls;
        if (r == 63) lsh1 = ls;
    }
    __syncthreads();

    // ---- weighted accumulation from registers; w read once from LDS ----
    float acc8[8] = {0.f, 0.f, 0.f, 0.f, 0.f, 0.f, 0.f, 0.f};
#pragma unroll
    for (int it = 0; it < 8; ++it) {
        const int r = it * 8 + wave * 2 + half;
        const float w = im[2 * r];                      // e_r (unnormalized)
        const fvec4 a0 = xq[it][0], a1 = xq[it][1];
        acc8[0] = fmaf(w, a0[0], acc8[0]); acc8[1] = fmaf(w, a0[1], acc8[1]);
        acc8[2] = fmaf(w, a0[2], acc8[2]); acc8[3] = fmaf(w, a0[3], acc8[3]);
        acc8[4] = fmaf(w, a1[0], acc8[4]); acc8[5] = fmaf(w, a1[1], acc8[5]);
        acc8[6] = fmaf(w, a1[2], acc8[6]); acc8[7] = fmaf(w, a1[3], acc8[7]);
    }

    // ---- merge 8 (wave,half) slots via LDS; lane owns d0 block + 128+d0 block ----
    const int slot = wave * 2 + half;
    float* wp = &ldsw[slot * 264];
    *(fvec4*)(wp + d0)       = (fvec4){acc8[0], acc8[1], acc8[2], acc8[3]};
    *(fvec4*)(wp + 128 + d0) = (fvec4){acc8[4], acc8[5], acc8[6], acc8[7]};
    __syncthreads();

    float accd = 0.f;
#pragma unroll
    for (int s = 0; s < 8; ++s) accd += ldsw[s * 264 + tid];

    float* pb = part + (size_t)blk * PSTR;
    if (tid == 0) pb[0] = lsh0 + lsh1;
    pb[16 + tid] = accd;                  // 64B-aligned 1KiB wave write
}

// Merge SEG partials per batch row. Pure sums (no exp, no max-shift).
// 64 blocks x 1024 threads: 4 segment-groups x 256 d-columns per block,
// 8-deep coalesced reads + tiny LDS tree.
__global__ __launch_bounds__(1024)
void combine_kernel(const float* __restrict__ part, float* __restrict__ out)
{
    __shared__ float red[4 * DD];
    __shared__ float dred[4];
    const int b = blockIdx.x;
    const int d = threadIdx.x & (DD - 1);
    const int g = threadIdx.x >> 8;       // segment-group 0..3
    const float* base = part + (size_t)b * SEG * PSTR;
    float den = 0.f, num = 0.f;
#pragma unroll
    for (int s = 0; s < 8; ++s) {
        const float* p = base + (size_t)(g * 8 + s) * PSTR;
        den += p[0];          // broadcast read
        num += p[16 + d];     // coalesced, 64B-aligned
    }
    red[g * DD + d] = num;
    if (d == 0) dred[g] = den;
    __syncthreads();
    if (g == 0) {
        const float n  = red[d] + red[DD + d] + red[2 * DD + d] + red[3 * DD + d];
        const float dn = dred[0] + dred[1] + dred[2] + dred[3];
        out[(size_t)b * DD + d] = n / dn;
    }
}

extern "C" void kernel_launch(void* const* d_in, const int* in_sizes, int n_in,
                              void* d_out, int out_size, void* d_ws, size_t ws_size,
                              hipStream_t stream) {
    const float* x_temp = (const float*)d_in[0];
    const float* x_fea  = (const float*)d_in[1];
    const int*   mask   = (const int*)d_in[2];
    const float* W_temp = (const float*)d_in[3];
    const float* b_temp = (const float*)d_in[4];
    const float* W_fea  = (const float*)d_in[5];
    const float* b_fea  = (const float*)d_in[6];
    // d_in[7] = b : constant across T, cancels in softmax — unused.
    const float* uw     = (const float*)d_in[8];

    float* part = (float*)d_ws;   // 2048 x 272 floats ~2.23 MB
    float* out  = (float*)d_out;

    seg_kernel<<<BB * SEG, 256, 0, stream>>>(x_temp, x_fea, mask, W_temp,
                                             b_temp, W_fea, b_fea, uw, part);
    combine_kernel<<<BB, 1024, 0, stream>>>(part, out);
}

// Round 7
// 197.254 us; speedup vs baseline: 1.0229x; 1.0229x over previous
//
#include <hip/hip_runtime.h>
#include <hip/hip_bf16.h>
#include <math.h>

// B,T,D,H = 64,2048,256,5
constexpr int BB   = 64;
constexpr int TT   = 2048;
constexpr int DD   = 256;
constexpr int HH   = 5;
constexpr int SEG  = 32;             // segments per batch row
constexpr int TSEG = TT / SEG;       // 64 timesteps per block
constexpr int PSTR = 272;            // partial row stride: [0]=l, [16+d]=acc (64B-aligned)

typedef float fvec4 __attribute__((ext_vector_type(4)));  // nontemporal-load-able

// fast tanh: 1 - 2/(e^{2x}+1). |err| ~1e-6, threshold is 1.7e-3.
__device__ __forceinline__ float ftanh(float x) {
    float e = __expf(2.0f * x);
    return 1.0f - 2.0f * __builtin_amdgcn_rcpf(e + 1.0f);
}

// DPP add on the VALU pipe (vs __shfl_xor -> ds_swizzle on the LDS pipe).
template <int CTRL>
__device__ __forceinline__ float dpp_add(float x) {
    int s = __builtin_amdgcn_update_dpp(0, __float_as_int(x), CTRL, 0xf, 0xf, true);
    return x + __int_as_float(s);
}
// 32-lane-half sum via row_shr 1/2/4/8 + row_bcast15. Valid in lanes 31 and 63.
__device__ __forceinline__ float half_sum_dpp(float v) {
    v = dpp_add<0x111>(v);   // row_shr:1
    v = dpp_add<0x112>(v);   // row_shr:2
    v = dpp_add<0x114>(v);   // row_shr:4
    v = dpp_add<0x118>(v);   // row_shr:8
    v = dpp_add<0x142>(v);   // row_bcast15 -> lane31 = sum(0..31), lane63 = sum(32..63)
    return v;
}

// One block = (b, 64-timestep segment). x register-resident end-to-end.
// |intermed| <= sum|uwr| ~ 0.5 -> softmax WITHOUT max-shift; partials are
// pure sums. Cross-segment merge in a second kernel.
//
// R5 (best, 197.2us): contiguous NT lane mapping — lane owns d0..d0+3 and
// 128+d0..+3; each load instruction covers a gap-free 512B wave footprint
// (gapped NT mapping double-fetched DRAM sectors). Single-pass dot with
// both W fragments resident; launch_bounds(256,3).
// R6 FAILED (+4.6us): two-pass dot for 4 blocks/CU — doubled the serial
// DPP-reduce chains; occupancy gain didn't cover it. Reverted.
// R7 = R5 + PSTR 272 (64B-aligned part rows, orthogonal keep from R6).
__global__ __launch_bounds__(256, 3)
void seg_kernel(const float* __restrict__ x_temp,
                const float* __restrict__ x_fea,
                const int* __restrict__ mask,            // bool -> int32 per harness
                const float* __restrict__ W_temp,        // (D,H) row-major
                const float* __restrict__ b_temp,
                const float* __restrict__ W_fea,         // (1,H)
                const float* __restrict__ b_fea,
                const float* __restrict__ uw,            // (H,H)
                float* __restrict__ part)                // (B*SEG, PSTR)
{
    __shared__ alignas(16) float im[2 * TSEG];     // interleaved {e_r, maskf_r}
    __shared__ alignas(16) float phl[TSEG][6];     // reduced dots ph[r][h] (+pad)
    __shared__ float lsh0, lsh1;                   // half lsums (rows 0..31 / 32..63)
    __shared__ alignas(16) float ldsw[8 * 264];    // per-(wave,half) acc partials

    const int tid  = threadIdx.x;
    const int l    = tid & 63;
    const int wave = tid >> 6;
    const int half = l >> 5;
    const int l32  = l & 31;
    const int blk  = blockIdx.x;
    const int b    = blk >> 5;          // blk / SEG
    const int seg  = blk & (SEG - 1);
    const int t0   = seg * TSEG;
    const size_t rowbase = (size_t)b * TT;
    const float* xbase = x_temp + (rowbase + t0) * (size_t)DD;

    if (tid < TSEG) im[2 * tid + 1] = mask[rowbase + t0 + tid] ? 1.0f : 0.0f;

    // ---- stage: 8 rows per (wave,half); lane owns d0..d0+3 and 128+d0..+3 ----
    const int d0 = l32 * 4;
    fvec4 xq[8][2];
#pragma unroll
    for (int it = 0; it < 8; ++it) {
        const float* p = xbase + (it * 8 + wave * 2 + half) * DD;
        xq[it][0] = __builtin_nontemporal_load((const fvec4*)(p + d0));
        xq[it][1] = __builtin_nontemporal_load((const fvec4*)(p + 128 + d0));
    }

    // W rows d0..d0+3: 20 consecutive floats at W_temp + d0*5;
    // W rows 128+d0..: 20 floats at W_temp + (128+d0)*5. Both resident.
    float wv0[20], wv1[20];
    {
        const fvec4* wp0 = (const fvec4*)(W_temp + d0 * HH);
        const fvec4* wp1 = (const fvec4*)(W_temp + (128 + d0) * HH);
#pragma unroll
        for (int q = 0; q < 5; ++q) { ((fvec4*)wv0)[q] = wp0[q]; ((fvec4*)wv1)[q] = wp1[q]; }
    }

    // ---- dot + DPP 32-half reduce; lanes 31/63 park ph[5] in LDS ----
#pragma unroll
    for (int it = 0; it < 8; ++it) {
        const int r = it * 8 + wave * 2 + half;
        const fvec4 a0 = xq[it][0], a1 = xq[it][1];
#pragma unroll
        for (int h = 0; h < HH; ++h) {
            float ph = a0[0] * wv0[0 * HH + h] + a0[1] * wv0[1 * HH + h]
                     + a0[2] * wv0[2 * HH + h] + a0[3] * wv0[3 * HH + h]
                     + a1[0] * wv1[0 * HH + h] + a1[1] * wv1[1 * HH + h]
                     + a1[2] * wv1[2 * HH + h] + a1[3] * wv1[3 * HH + h];
            ph = half_sum_dpp(ph);                // valid in lanes 31 / 63
            if (l32 == 31) phl[r][h] = ph;        // 2 lanes, unique r per (it,wave,half)
        }
    }
    __syncthreads();

    // ---- finish phase: ONE full wave (lanes 0..63 = rows 0..63) ----
    if (tid < TSEG) {
        const int r = tid;
        float wfea[HH], bfea[HH], btmp[HH], uwr[HH];
#pragma unroll
        for (int h = 0; h < HH; ++h) {
            wfea[h] = W_fea[h]; bfea[h] = b_fea[h]; btmp[h] = b_temp[h];
            float s = 0.f;
#pragma unroll
            for (int h2 = 0; h2 < HH; ++h2) s += uw[h * HH + h2];
            uwr[h] = s;  // sum(hadamard@uw+b,-1) = hadamard.uwr + const (cancels)
        }
        const float xf = x_fea[rowbase + t0 + r];
        float inter = 0.f;
#pragma unroll
        for (int h = 0; h < HH; ++h)
            inter += ftanh(phl[r][h] + btmp[h]) * ftanh(xf * wfea[h] + bfea[h]) * uwr[h];
        const float e = im[2 * r + 1] * __expf(inter);  // masked exp, no max-shift
        im[2 * r] = e;
        const float ls = half_sum_dpp(e);   // lane31: rows 0..31, lane63: rows 32..63
        if (r == 31) lsh0 = ls;
        if (r == 63) lsh1 = ls;
    }
    __syncthreads();

    // ---- weighted accumulation from registers; w read once from LDS ----
    float acc8[8] = {0.f, 0.f, 0.f, 0.f, 0.f, 0.f, 0.f, 0.f};
#pragma unroll
    for (int it = 0; it < 8; ++it) {
        const int r = it * 8 + wave * 2 + half;
        const float w = im[2 * r];                      // e_r (unnormalized)
        const fvec4 a0 = xq[it][0], a1 = xq[it][1];
        acc8[0] = fmaf(w, a0[0], acc8[0]); acc8[1] = fmaf(w, a0[1], acc8[1]);
        acc8[2] = fmaf(w, a0[2], acc8[2]); acc8[3] = fmaf(w, a0[3], acc8[3]);
        acc8[4] = fmaf(w, a1[0], acc8[4]); acc8[5] = fmaf(w, a1[1], acc8[5]);
        acc8[6] = fmaf(w, a1[2], acc8[6]); acc8[7] = fmaf(w, a1[3], acc8[7]);
    }

    // ---- merge 8 (wave,half) slots via LDS; lane owns d0 block + 128+d0 block ----
    const int slot = wave * 2 + half;
    float* wp = &ldsw[slot * 264];
    *(fvec4*)(wp + d0)       = (fvec4){acc8[0], acc8[1], acc8[2], acc8[3]};
    *(fvec4*)(wp + 128 + d0) = (fvec4){acc8[4], acc8[5], acc8[6], acc8[7]};
    __syncthreads();

    float accd = 0.f;
#pragma unroll
    for (int s = 0; s < 8; ++s) accd += ldsw[s * 264 + tid];

    float* pb = part + (size_t)blk * PSTR;
    if (tid == 0) pb[0] = lsh0 + lsh1;
    pb[16 + tid] = accd;                  // 64B-aligned 1KiB wave write
}

// Merge SEG partials per batch row. Pure sums (no exp, no max-shift).
// 64 blocks x 1024 threads: 4 segment-groups x 256 d-columns per block,
// 8-deep coalesced reads + tiny LDS tree.
__global__ __launch_bounds__(1024)
void combine_kernel(const float* __restrict__ part, float* __restrict__ out)
{
    __shared__ float red[4 * DD];
    __shared__ float dred[4];
    const int b = blockIdx.x;
    const int d = threadIdx.x & (DD - 1);
    const int g = threadIdx.x >> 8;       // segment-group 0..3
    const float* base = part + (size_t)b * SEG * PSTR;
    float den = 0.f, num = 0.f;
#pragma unroll
    for (int s = 0; s < 8; ++s) {
        const float* p = base + (size_t)(g * 8 + s) * PSTR;
        den += p[0];          // broadcast read
        num += p[16 + d];     // coalesced, 64B-aligned
    }
    red[g * DD + d] = num;
    if (d == 0) dred[g] = den;
    __syncthreads();
    if (g == 0) {
        const float n  = red[d] + red[DD + d] + red[2 * DD + d] + red[3 * DD + d];
        const float dn = dred[0] + dred[1] + dred[2] + dred[3];
        out[(size_t)b * DD + d] = n / dn;
    }
}

extern "C" void kernel_launch(void* const* d_in, const int* in_sizes, int n_in,
                              void* d_out, int out_size, void* d_ws, size_t ws_size,
                              hipStream_t stream) {
    const float* x_temp = (const float*)d_in[0];
    const float* x_fea  = (const float*)d_in[1];
    const int*   mask   = (const int*)d_in[2];
    const float* W_temp = (const float*)d_in[3];
    const float* b_temp = (const float*)d_in[4];
    const float* W_fea  = (const float*)d_in[5];
    const float* b_fea  = (const float*)d_in[6];
    // d_in[7] = b : constant across T, cancels in softmax — unused.
    const float* uw     = (const float*)d_in[8];

    float* part = (float*)d_ws;   // 2048 x 272 floats ~2.23 MB
    float* out  = (float*)d_out;

    seg_kernel<<<BB * SEG, 256, 0, stream>>>(x_temp, x_fea, mask, W_temp,
                                             b_temp, W_fea, b_fea, uw, part);
    combine_kernel<<<BB, 1024, 0, stream>>>(part, out);
}